// Round 5
// baseline (246.059 us; speedup 1.0000x reference)
//
#include <hip/hip_runtime.h>
#include <stdint.h>

// ---------------------------------------------------------------------------
// IEViT adaptive patch embedding, MI355X/gfx950.  Round 5: 2-phase prefetch.
//   even patch i=2p  -> 4 sub tokens (16x16, averaged kernel)
//   odd  patch i=2p+1-> 1 full token (32x32, full kernel)
//   tokens per pair p: [sub(0,0),sub(0,1),sub(1,0),sub(1,1),full] at 5p..5p+4
// GEMM-full: M=4096 K=3072 N=768 -> split-K=4 (bf16 partials + reduce)
// GEMM-sub:  M=16384 K=768 N=768 -> direct write
// 1536 uniform blocks, 128x128 tile, BK=32, 24 K-steps, double-buffered LDS:
//   step s: {issue B-glds(next)+A-loads(next)} -> compute(cur) -> {cvt+ds_write
//   A(next)} -> barrier.  Loads issued a full step before their drain (T3-min).
// A LDS rows padded to 40 ushorts (80 B) -> conflict-free frag reads.
// B LDS linear (glds) with chunk-XOR swizzle done on the GLOBAL source and
// undone on the read: slot (row,ch) holds logical chunk ch^(row&3).
// ---------------------------------------------------------------------------

typedef __attribute__((ext_vector_type(8))) short bf16x8;
typedef __attribute__((ext_vector_type(8))) unsigned short ushort8;
typedef __attribute__((ext_vector_type(4))) float f32x4;

__device__ __forceinline__ unsigned short f2bf(float f) {
  union { float f; unsigned u; } v; v.f = f;
  return (unsigned short)((v.u + 0x7fffu + ((v.u >> 16) & 1u)) >> 16);  // RNE
}
__device__ __forceinline__ float bf2f(unsigned short h) {
  union { unsigned u; float f; } v; v.u = ((unsigned)h) << 16; return v.f;
}

// ---- weight prep: [0,2304) cast Wf; [2304,2880) build Ws -------------------
__global__ __launch_bounds__(256) void prep_w(const float* __restrict__ pw,
                                              unsigned short* __restrict__ Wf,
                                              unsigned short* __restrict__ Ws) {
  int bid = blockIdx.x, t = threadIdx.x;
  if (bid < 2304) {                      // cast patch_weight -> bf16 (B^T layout)
    int g = bid * 256 + t;               // 589,824 float4 groups
    float4 v = ((const float4*)pw)[g];
    ((ushort4*)Wf)[g] = make_ushort4(f2bf(v.x), f2bf(v.y), f2bf(v.z), f2bf(v.w));
  } else {                               // w_sub: reshape(E,C,2,2,16,16).mean(2,3)
    int g = (bid - 2304) * 256 + t;      // w_sub[e,c,s,t] averages rows
    int e = g / 192;                     // {s>>1, 8+, 16+, 24+} of col 16*(s&1)+t
    int rem = g - e * 192;
    int cc = rem >> 6, r2 = rem & 63, s = r2 >> 2, t4 = r2 & 3;
    const float* base = pw + ((size_t)((e * 3 + cc) * 32 + (s >> 1)) * 32
                              + 16 * (s & 1) + 4 * t4);
    float4 q0 = *(const float4*)(base);
    float4 q1 = *(const float4*)(base + 8 * 32);
    float4 q2 = *(const float4*)(base + 16 * 32);
    float4 q3 = *(const float4*)(base + 24 * 32);
    ((ushort4*)Ws)[g] = make_ushort4(
        f2bf(0.25f * (q0.x + q1.x + q2.x + q3.x)),
        f2bf(0.25f * (q0.y + q1.y + q2.y + q3.y)),
        f2bf(0.25f * (q0.z + q1.z + q2.z + q3.z)),
        f2bf(0.25f * (q0.w + q1.w + q2.w + q3.w)));
  }
}

// ---- fused GEMM: 2-phase double-buffered, A from x (f32->bf16), B via glds -
__global__ __launch_bounds__(256, 3) void gemm_fused(
    const float* __restrict__ x,
    const unsigned short* __restrict__ Wf, const unsigned short* __restrict__ Ws,
    const float* __restrict__ bias, unsigned short* __restrict__ Pf,
    float* __restrict__ out) {
  __shared__ unsigned short Asm[2][128 * 40];   // padded: 80 B rows, conflict-free
  __shared__ unsigned short Bsm[2][128 * 32];   // linear dest (glds), XOR chunks
  // LDS total: 2*5120*2 + 2*4096*2 = 36,864 B -> 4 blocks/CU LDS-limit

  // XCD swizzle: nwg=1536 = 8*192 (bijective); the 6 bn of one (bm,kc) group
  // land on one XCD -> x re-reads are L2-local.
  int bid = (blockIdx.x & 7) * 192 + (blockIdx.x >> 3);

  const unsigned short* Bbase;
  int rsB, bm, bn, kofs, which, kc = 0;
  int ccsh, iish, iimask, jjmask;
  if (bid < 768) {                 // full GEMM partial: grp=(bm,kc), 6 bn each
    which = 0;
    int grp = bid / 6; bn = bid - grp * 6;
    bm = grp >> 2; kc = grp & 3;
    rsB = 3072; kofs = kc * 768;
    Bbase = Wf;
    ccsh = 10; iish = 5; iimask = 31; jjmask = 31;
  } else {                         // sub GEMM: direct
    which = 1;
    int id = bid - 768;
    bm = id / 6; bn = id - bm * 6;
    rsB = 768; kofs = 0;
    Bbase = Ws;
    ccsh = 8; iish = 4; iimask = 15; jjmask = 15;
  }

  int t = threadIdx.x;
  int lane = t & 63;
  int wv = t >> 6, wr = wv >> 1, wc = wv & 1;   // 2x2 waves, 64x64 each
  int lr = lane & 15, lk = lane >> 4;

  // staging slots: slot = t + 256*is, row = slot>>2 (0..127), ch = slot&3
  // (8 contiguous f32 in x per slot -- verified: 8 | 16 | 32 divisibility)
  int abase[2], kA[2], awr[2];
  const unsigned short* bsrc[2];
#pragma unroll
  for (int is = 0; is < 2; ++is) {
    int slot = t + 256 * is;
    int row = slot >> 2, ch = slot & 3;
    int m = bm * 128 + row;
    int b, r, cp, extra;
    if (which == 0) {
      b = m >> 7; int p = m & 127; int i = 2 * p + 1;
      r = i >> 4; cp = i & 15; extra = 0;
    } else {
      b = m >> 9; int q = m & 511; int p = q >> 2, sq = q & 3;
      int i = 2 * p; r = i >> 4; cp = i & 15;
      extra = (sq >> 1) * 8192 + (sq & 1) * 16;
    }
    abase[is] = b * 786432 + r * 16384 + cp * 32 + extra;
    kA[is] = kofs + ch * 8;                       // logical k of this slot
    awr[is] = row * 40 + ch * 8;                  // padded A write offset (elems)
    // B: linear LDS slot (row,ch) must hold logical chunk ch^(row&3)
    bsrc[is] = Bbase + (size_t)(bn * 128 + row) * rsB + kofs + ((ch ^ (row & 3)) * 8);
  }

  f32x4 acc[4][4];
#pragma unroll
  for (int mm = 0; mm < 4; ++mm)
#pragma unroll
    for (int nn = 0; nn < 4; ++nn) acc[mm][nn] = (f32x4){0.f, 0.f, 0.f, 0.f};

  // ---- prologue: stage k-step 0 into buffer 0
  {
    float4 va[2][2];
#pragma unroll
    for (int is = 0; is < 2; ++is)
      __builtin_amdgcn_global_load_lds(
          (const __attribute__((address_space(1))) void*)(bsrc[is]),
          (__attribute__((address_space(3))) void*)(&Bsm[0][(t + 256 * is) * 8]),
          16, 0, 0);
#pragma unroll
    for (int is = 0; is < 2; ++is) {
      int kl = kA[is];
      int koff = (kl >> ccsh) * 262144 + ((kl >> iish) & iimask) * 512 + (kl & jjmask);
      const float4* s4 = (const float4*)(x + abase[is] + koff);
      va[is][0] = s4[0]; va[is][1] = s4[1];
    }
#pragma unroll
    for (int is = 0; is < 2; ++is) {
      ushort8 v;
      v[0] = f2bf(va[is][0].x); v[1] = f2bf(va[is][0].y);
      v[2] = f2bf(va[is][0].z); v[3] = f2bf(va[is][0].w);
      v[4] = f2bf(va[is][1].x); v[5] = f2bf(va[is][1].y);
      v[6] = f2bf(va[is][1].z); v[7] = f2bf(va[is][1].w);
      *(ushort8*)&Asm[0][awr[is]] = v;
    }
    __syncthreads();
  }

  // ---- main loop: 24 steps of BK=32
  for (int s = 0; s < 24; ++s) {
    int cur = s & 1, nxt = cur ^ 1;
    float4 va[2][2];
    if (s < 23) {                        // prefetch next k-step (issue-early)
      int k0n = (s + 1) * 32;
#pragma unroll
      for (int is = 0; is < 2; ++is)
        __builtin_amdgcn_global_load_lds(
            (const __attribute__((address_space(1))) void*)(bsrc[is] + k0n),
            (__attribute__((address_space(3))) void*)(&Bsm[nxt][(t + 256 * is) * 8]),
            16, 0, 0);
#pragma unroll
      for (int is = 0; is < 2; ++is) {
        int kl = kA[is] + k0n;
        int koff = (kl >> ccsh) * 262144 + ((kl >> iish) & iimask) * 512 + (kl & jjmask);
        const float4* s4 = (const float4*)(x + abase[is] + koff);
        va[is][0] = s4[0]; va[is][1] = s4[1];
      }
    }
    // compute current buffer
    bf16x8 af[4], bfr[4];
#pragma unroll
    for (int mm = 0; mm < 4; ++mm) {
      int rowA = wr * 64 + mm * 16 + lr;
      af[mm] = *(const bf16x8*)&Asm[cur][rowA * 40 + lk * 8];
    }
#pragma unroll
    for (int nn = 0; nn < 4; ++nn) {
      int rowB = wc * 64 + nn * 16 + lr;   // rowB&3 == lr&3
      bfr[nn] = *(const bf16x8*)&Bsm[cur][rowB * 32 + ((lk ^ (lr & 3)) * 8)];
    }
#pragma unroll
    for (int mm = 0; mm < 4; ++mm)
#pragma unroll
      for (int nn = 0; nn < 4; ++nn)
        acc[mm][nn] = __builtin_amdgcn_mfma_f32_16x16x32_bf16(af[mm], bfr[nn], acc[mm][nn], 0, 0, 0);
    if (s < 23) {                        // write-late: convert + ds_write A(next)
#pragma unroll
      for (int is = 0; is < 2; ++is) {
        ushort8 v;
        v[0] = f2bf(va[is][0].x); v[1] = f2bf(va[is][0].y);
        v[2] = f2bf(va[is][0].z); v[3] = f2bf(va[is][0].w);
        v[4] = f2bf(va[is][1].x); v[5] = f2bf(va[is][1].y);
        v[6] = f2bf(va[is][1].z); v[7] = f2bf(va[is][1].w);
        *(ushort8*)&Asm[nxt][awr[is]] = v;
      }
    }
    __syncthreads();   // drains glds (vmcnt) + ds_writes (lgkm): nxt ready
  }

  // epilogue: C/D mapping col=lane&15, row=(lane>>4)*4+reg [m89/m91 verified]
#pragma unroll
  for (int mm = 0; mm < 4; ++mm) {
    int trow = wr * 64 + mm * 16 + lk * 4;
#pragma unroll
    for (int reg = 0; reg < 4; ++reg) {
      int grow = bm * 128 + trow + reg;
      if (which == 0) {            // bf16 partial (no bias) -> Pf[kc][grow][col]
        unsigned short* pdst = Pf + ((size_t)(kc * 4096 + grow)) * 768;
#pragma unroll
        for (int nn = 0; nn < 4; ++nn) {
          int gcol = bn * 128 + wc * 64 + nn * 16 + lr;
          pdst[gcol] = f2bf(acc[mm][nn][reg]);
        }
      } else {                     // A_sub row -> token 5p+s, direct + bias
        int b = grow >> 9, tt2 = grow & 511, p = tt2 >> 2, sq = tt2 & 3;
        size_t obase = (size_t)(b * 640 + 5 * p + sq) * 768;
#pragma unroll
        for (int nn = 0; nn < 4; ++nn) {
          int gcol = bn * 128 + wc * 64 + nn * 16 + lr;
          out[obase + gcol] = acc[mm][nn][reg] + bias[gcol];
        }
      }
    }
  }
}

// ---- reduce split-K partials + bias, scatter to full-token rows ------------
__global__ __launch_bounds__(256) void reduce_full(
    const unsigned short* __restrict__ Pf, const float* __restrict__ bias,
    float* __restrict__ out) {
  int q = blockIdx.x * 256 + threadIdx.x;   // 786,432 float4 outputs
  int m = q / 192, c4 = q - m * 192;
  float4 sacc = ((const float4*)bias)[c4];
#pragma unroll
  for (int kc = 0; kc < 4; ++kc) {
    ushort4 u = ((const ushort4*)(Pf + ((size_t)(kc * 4096 + m)) * 768))[c4];
    sacc.x += bf2f(u.x); sacc.y += bf2f(u.y);
    sacc.z += bf2f(u.z); sacc.w += bf2f(u.w);
  }
  int b = m >> 7, p = m & 127;
  size_t obase = (size_t)(b * 640 + 5 * p + 4) * 768;
  ((float4*)(out + obase))[c4] = sacc;
}

extern "C" void kernel_launch(void* const* d_in, const int* in_sizes, int n_in,
                              void* d_out, int out_size, void* d_ws, size_t ws_size,
                              hipStream_t stream) {
  const float* x  = (const float*)d_in[0];
  // d_in[1] importance_w, d_in[4] num_patches: structure is static (see header)
  const float* pw = (const float*)d_in[2];
  const float* pb = (const float*)d_in[3];
  float* out = (float*)d_out;

  unsigned short* Wf = (unsigned short*)d_ws;   // 768*3072   =  2,359,296 elems
  unsigned short* Ws = Wf + 2359296;            // 768*768    =    589,824
  unsigned short* Pf = Ws + 589824;             // 4*4096*768 = 12,582,912
  // total ws: 31,064,064 bytes

  prep_w<<<2880, 256, 0, stream>>>(pw, Wf, Ws);
  gemm_fused<<<1536, 256, 0, stream>>>(x, Wf, Ws, pb, Pf, out);
  reduce_full<<<3072, 256, 0, stream>>>(Pf, pb, out);
}